// Round 1
// baseline (74.883 us; speedup 1.0000x reference)
//
#include <hip/hip_runtime.h>
#include <math.h>

// Problem constants (fixed by setup_inputs):
//   k_b=4, c_out=64, c_in=8, N=4096, m=8, ker=N/(2m)=256, c=2*pi*m/N, ker*c=pi
// Analytic collapse (derivation in session journal):
//   sr[b,o,mu] = -(cos(c*mu)*Gr[b,o] + sin(c*mu)*Hr[b,o])
//   si[b,o,mu] = -(cos(c*mu)*Gi[b,o] + sin(c*mu)*Hi[b,o])
// with, per (b,i):  Fcr=sum_t zr*cos(ct), Fsr=sum_t zr*sin(ct),
//                   Fci=sum_t zi*cos(ct), Fsi=sum_t zi*sin(ct)
// and, per (o,i):   P=|A|cos(beta), Q=|A|sin(beta):
//   Gr = sum_i(-P*Fcr + Q*Fsr + Q*Fci + P*Fsi)
//   Hr = sum_i(-P*Fsr - Q*Fcr + Q*Fsi - P*Fci)
//   Gi = sum_i(-Q*Fcr - P*Fsr - P*Fci + Q*Fsi)
//   Hi = sum_i( P*Fcr - Q*Fsr - Q*Fci - P*Fsi)
// Then mag=sqrt(sr^2+si^2); gate=sigmoid(mag+bias)/(mag+1e-5); out = gate*{sr,si}.

#define KB   4
#define COUT 64
#define CIN  8
#define NN   4096
#define PI_F 3.14159265358979323846f

// ---------------- Kernel A: Fourier sums per (b,i) ----------------
// grid: KB*CIN = 32 blocks, 256 threads. F[pair*4 + {cr,sr,ci,si}] -> d_ws
__global__ void f_reduce_kernel(const float* __restrict__ zr,
                                const float* __restrict__ zi,
                                const int* __restrict__ m_ptr,
                                float* __restrict__ F) {
    const int pair = blockIdx.x;          // b*CIN + i
    const int tid  = threadIdx.x;         // 0..255
    const int m    = *m_ptr;
    const float cstep = PI_F / 2048.0f;   // c = 2*pi*m/N -> angle = (m*t mod N)*pi*2/N
    const float* xr = zr + pair * NN;
    const float* xi = zi + pair * NN;

    float fcr = 0.f, fsr = 0.f, fci = 0.f, fsi = 0.f;
    #pragma unroll
    for (int it = 0; it < NN / 256; ++it) {
        int t = tid + it * 256;
        int r = (m * t) & (NN - 1);       // exact phase reduction mod 2*pi
        float ang = cstep * (float)r;
        float s, cc;
        sincosf(ang, &s, &cc);
        float vr = xr[t], vi = xi[t];
        fcr += vr * cc;  fsr += vr * s;
        fci += vi * cc;  fsi += vi * s;
    }
    // wave(64) shuffle reduce, then LDS across 4 waves
    #pragma unroll
    for (int off = 32; off > 0; off >>= 1) {
        fcr += __shfl_down(fcr, off);
        fsr += __shfl_down(fsr, off);
        fci += __shfl_down(fci, off);
        fsi += __shfl_down(fsi, off);
    }
    __shared__ float red[4][4];
    int wave = tid >> 6, lane = tid & 63;
    if (lane == 0) {
        red[wave][0] = fcr; red[wave][1] = fsr;
        red[wave][2] = fci; red[wave][3] = fsi;
    }
    __syncthreads();
    if (tid == 0) {
        float a = red[0][0] + red[1][0] + red[2][0] + red[3][0];
        float b = red[0][1] + red[1][1] + red[2][1] + red[3][1];
        float c2 = red[0][2] + red[1][2] + red[2][2] + red[3][2];
        float d = red[0][3] + red[1][3] + red[2][3] + red[3][3];
        F[pair * 4 + 0] = a;
        F[pair * 4 + 1] = b;
        F[pair * 4 + 2] = c2;
        F[pair * 4 + 3] = d;
    }
}

// ---------------- Kernel B: outputs ----------------
// grid: KB*COUT = 256 blocks, 256 threads; each block does one (b,o) row.
__global__ void out_kernel(const float* __restrict__ A,
                           const float* __restrict__ beta,
                           const float* __restrict__ bias,
                           const int* __restrict__ m_ptr,
                           const float* __restrict__ F,
                           float* __restrict__ out) {
    const int blk = blockIdx.x;           // b*COUT + o
    const int b = blk >> 6, o = blk & (COUT - 1);
    const int m = *m_ptr;

    float Gr = 0.f, Hr = 0.f, Gi = 0.f, Hi = 0.f;
    #pragma unroll
    for (int i = 0; i < CIN; ++i) {
        float a  = fabsf(A[o * CIN + i]);
        float be = beta[o * CIN + i];
        float sb, cb;
        sincosf(be, &sb, &cb);
        float P = a * cb, Q = a * sb;
        const float* f = F + (b * CIN + i) * 4;
        float Fcr = f[0], Fsr = f[1], Fci = f[2], Fsi = f[3];
        Gr += -P * Fcr + Q * Fsr + Q * Fci + P * Fsi;
        Hr += -P * Fsr - Q * Fcr + Q * Fsi - P * Fci;
        Gi += -Q * Fcr - P * Fsr - P * Fci + Q * Fsi;
        Hi +=  P * Fcr - Q * Fsr - Q * Fci - P * Fsi;
    }
    const float bo = bias[o];
    const float cstep = PI_F / 2048.0f;
    const int base = blk << 12;                    // *4096
    const int half = KB * COUT * NN;               // offset of output 1

    for (int mu = threadIdx.x; mu < NN; mu += 256) {
        int r = (m * mu) & (NN - 1);
        float ang = cstep * (float)r;
        float smu, cmu;
        sincosf(ang, &smu, &cmu);
        float sr = -(cmu * Gr + smu * Hr);
        float si = -(cmu * Gi + smu * Hi);
        float mag = sqrtf(sr * sr + si * si);
        float gate = 1.0f / (1.0f + __expf(-(mag + bo))) / (mag + 1e-5f);
        out[base + mu]        = gate * sr;
        out[half + base + mu] = gate * si;
    }
}

extern "C" void kernel_launch(void* const* d_in, const int* in_sizes, int n_in,
                              void* d_out, int out_size, void* d_ws, size_t ws_size,
                              hipStream_t stream) {
    const float* z_real = (const float*)d_in[0];
    const float* z_imag = (const float*)d_in[1];
    const float* A      = (const float*)d_in[2];
    const float* beta   = (const float*)d_in[3];
    const float* bias   = (const float*)d_in[4];
    const int*   m_ptr  = (const int*)d_in[5];
    float* out = (float*)d_out;
    float* F   = (float*)d_ws;   // 32*4 floats

    f_reduce_kernel<<<KB * CIN, 256, 0, stream>>>(z_real, z_imag, m_ptr, F);
    out_kernel<<<KB * COUT, 256, 0, stream>>>(A, beta, bias, m_ptr, F, out);
}

// Round 2
// 71.166 us; speedup vs baseline: 1.0522x; 1.0522x over previous
//
#include <hip/hip_runtime.h>
#include <math.h>

// Problem constants (fixed by setup_inputs):
//   k_b=4, c_out=64, c_in=8, N=4096, m=8, ker=N/(2m)=256, c=2*pi*m/N, ker*c=pi
// Analytic collapse (derivation journal R0):
//   sr[b,o,mu] = -(cos(c*mu)*Gr[b,o] + sin(c*mu)*Hr[b,o])
//   si[b,o,mu] = -(cos(c*mu)*Gi[b,o] + sin(c*mu)*Hi[b,o])
// with per-(b,i) Fourier sums Fcr,Fsr,Fci,Fsi and per-(o,i) P=|A|cosb, Q=|A|sinb.
// All angles are exact multiples of 2*pi*(r/4096), r integer -> use HW
// v_sin_f32/v_cos_f32 (REVOLUTION input, ~1ulp on |x|<1) via builtins.

#define KB   4
#define COUT 64
#define CIN  8
#define NN   4096
#define INV_N (1.0f / 4096.0f)
#define INV_2PI 0.15915494309189535f

// ---------------- Kernel A: Fourier sums per (b,i) ----------------
// grid: KB*CIN = 32 blocks, 256 threads. F[pair*4 + {cr,sr,ci,si}] -> d_ws
__global__ void f_reduce_kernel(const float* __restrict__ zr,
                                const float* __restrict__ zi,
                                const int* __restrict__ m_ptr,
                                float* __restrict__ F) {
    const int pair = blockIdx.x;          // b*CIN + i
    const int tid  = threadIdx.x;         // 0..255
    const int m    = *m_ptr;
    const float4* xr = (const float4*)(zr + pair * NN);
    const float4* xi = (const float4*)(zi + pair * NN);

    float fcr = 0.f, fsr = 0.f, fci = 0.f, fsi = 0.f;
    #pragma unroll
    for (int it = 0; it < NN / 1024; ++it) {
        int vidx = it * 256 + tid;        // float4 index, coalesced
        float4 vr = xr[vidx];
        float4 vi = xi[vidx];
        int t0 = vidx * 4;
        #pragma unroll
        for (int j = 0; j < 4; ++j) {
            int r = (m * (t0 + j)) & (NN - 1);   // exact phase mod 1 revolution
            float rev = (float)r * INV_N;
            float s = __builtin_amdgcn_sinf(rev);
            float c = __builtin_amdgcn_cosf(rev);
            float a = (&vr.x)[j], b = (&vi.x)[j];
            fcr += a * c;  fsr += a * s;
            fci += b * c;  fsi += b * s;
        }
    }
    // wave(64) shuffle reduce, then LDS across 4 waves
    #pragma unroll
    for (int off = 32; off > 0; off >>= 1) {
        fcr += __shfl_down(fcr, off);
        fsr += __shfl_down(fsr, off);
        fci += __shfl_down(fci, off);
        fsi += __shfl_down(fsi, off);
    }
    __shared__ float red[4][4];
    int wave = tid >> 6, lane = tid & 63;
    if (lane == 0) {
        red[wave][0] = fcr; red[wave][1] = fsr;
        red[wave][2] = fci; red[wave][3] = fsi;
    }
    __syncthreads();
    if (tid == 0) {
        F[pair * 4 + 0] = red[0][0] + red[1][0] + red[2][0] + red[3][0];
        F[pair * 4 + 1] = red[0][1] + red[1][1] + red[2][1] + red[3][1];
        F[pair * 4 + 2] = red[0][2] + red[1][2] + red[2][2] + red[3][2];
        F[pair * 4 + 3] = red[0][3] + red[1][3] + red[2][3] + red[3][3];
    }
}

// ---------------- Kernel B: outputs ----------------
// grid: KB*COUT = 256 blocks, 256 threads; each block does one (b,o) row.
__global__ void out_kernel(const float* __restrict__ A,
                           const float* __restrict__ beta,
                           const float* __restrict__ bias,
                           const int* __restrict__ m_ptr,
                           const float* __restrict__ F,
                           float* __restrict__ out) {
    const int blk = blockIdx.x;           // b*COUT + o
    const int b = blk >> 6, o = blk & (COUT - 1);
    const int m = *m_ptr;

    float Gr = 0.f, Hr = 0.f, Gi = 0.f, Hi = 0.f;
    #pragma unroll
    for (int i = 0; i < CIN; ++i) {
        float a  = fabsf(A[o * CIN + i]);
        float rb = beta[o * CIN + i] * INV_2PI;      // radians -> revolutions
        float sb = __builtin_amdgcn_sinf(rb);
        float cb = __builtin_amdgcn_cosf(rb);
        float P = a * cb, Q = a * sb;
        const float* f = F + (b * CIN + i) * 4;
        float Fcr = f[0], Fsr = f[1], Fci = f[2], Fsi = f[3];
        Gr += -P * Fcr + Q * Fsr + Q * Fci + P * Fsi;
        Hr += -P * Fsr - Q * Fcr + Q * Fsi - P * Fci;
        Gi += -Q * Fcr - P * Fsr - P * Fci + Q * Fsi;
        Hi +=  P * Fcr - Q * Fsr - Q * Fci - P * Fsi;
    }
    const float bo = bias[o];
    const int base = blk << 12;                    // *4096
    const int half = KB * COUT * NN;               // offset of output 1

    #pragma unroll
    for (int k = 0; k < NN / 256; ++k) {
        int mu = threadIdx.x + k * 256;
        int r = (m * mu) & (NN - 1);
        float rev = (float)r * INV_N;
        float smu = __builtin_amdgcn_sinf(rev);
        float cmu = __builtin_amdgcn_cosf(rev);
        float sr = -(cmu * Gr + smu * Hr);
        float si = -(cmu * Gi + smu * Hi);
        float mag = sqrtf(sr * sr + si * si);
        float gate = 1.0f / (1.0f + __expf(-(mag + bo))) / (mag + 1e-5f);
        out[base + mu]        = gate * sr;
        out[half + base + mu] = gate * si;
    }
}

extern "C" void kernel_launch(void* const* d_in, const int* in_sizes, int n_in,
                              void* d_out, int out_size, void* d_ws, size_t ws_size,
                              hipStream_t stream) {
    const float* z_real = (const float*)d_in[0];
    const float* z_imag = (const float*)d_in[1];
    const float* A      = (const float*)d_in[2];
    const float* beta   = (const float*)d_in[3];
    const float* bias   = (const float*)d_in[4];
    const int*   m_ptr  = (const int*)d_in[5];
    float* out = (float*)d_out;
    float* F   = (float*)d_ws;   // 32*4 floats

    f_reduce_kernel<<<KB * CIN, 256, 0, stream>>>(z_real, z_imag, m_ptr, F);
    out_kernel<<<KB * COUT, 256, 0, stream>>>(A, beta, bias, m_ptr, F, out);
}